// Round 1
// baseline (117.112 us; speedup 1.0000x reference)
//
#include <hip/hip_runtime.h>

typedef unsigned short u16;
typedef __attribute__((ext_vector_type(8))) short short8;   // 8 x bf16 (4 VGPRs)
typedef __attribute__((ext_vector_type(4))) float floatx4;  // MFMA acc

#define WST 532     // fp32 stride of w rows: 532 mod 32 = 20 -> conflict-free q spread
#define BST 136     // u16 stride of Bt rows: 272 B, 16B-aligned rows
#define KCHUNK 128

__device__ __forceinline__ u16 f2bf_rne(float f) {
  unsigned u = __float_as_uint(f);
  u += 0x7fffu + ((u >> 16) & 1u);      // round-to-nearest-even
  return (u16)(u >> 16);
}

// One workgroup = one (b, sub) pair: GEMM of A(128x512) * B(512x64).
// A[r][c] = w[r%8][r/8 + c] (raw 0..255 window values, exact in bf16)
// B[c][o] = W[c][o] * 2/255 (bf16), zero-padded for c >= 496.
// out[r][o] = acc - colsum[o].
__global__ __launch_bounds__(256, 4) void byteformer_kernel(
    const int* __restrict__ x, const float* __restrict__ Wm,
    float* __restrict__ out) {
  __shared__ float wlds[8 * WST];
  __shared__ __align__(16) u16 Bt[64 * BST];   // Bt[o][klocal], bf16-scaled W
  __shared__ float part[256];
  __shared__ float csum[64];

  const int t = threadIdx.x;
  const int bid = blockIdx.x;                  // 0..2047 ; bid = b*8 + sub
  const long xbase = (long)bid * 512;

  // zero-pad w tail [512, WST) so padded-K A reads are finite
  if (t < 8 * (WST - 512)) {
    int q = t / (WST - 512), mm = 512 + t % (WST - 512);
    wlds[q * WST + mm] = 0.0f;
  }
  // stage w[q][m] as exact-integer fp32 (4B alignment => any Toeplitz offset readable)
  #pragma unroll
  for (int half = 0; half < 2; ++half) {
    int m = t + 256 * half;                    // 0..511
    int b0 = x[xbase + m] & 255;
    int b1 = (m == 511) ? 0 : (x[xbase + m + 1] & 255);  // per-subblock zero pad (ref semantics)
    #pragma unroll
    for (int q = 0; q < 8; ++q) {
      int wv = ((b0 << q) & 255) + (b1 >> (8 - q));
      wlds[q * WST + m] = (float)wv;
    }
  }

  const int wave = t >> 6;
  const int lane = t & 63;
  const int quad = lane >> 4;
  const int l16 = lane & 15;

  // A fragment addressing: row r = wave*32 + mt*16 + l16
  //   q = r & 7 = l16 & 7 ; p = r >> 3 = wave*4 + mt*2 + (l16>>3)
  const int qa = l16 & 7;
  const int p0 = wave * 4 + (l16 >> 3);
  const int aBase = qa * WST + p0 + 8 * quad;  // + mt*2 + k0 + j at use site

  floatx4 acc[2][4];
  #pragma unroll
  for (int mt = 0; mt < 2; ++mt)
    #pragma unroll
    for (int nt = 0; nt < 4; ++nt)
      acc[mt][nt] = floatx4{0.f, 0.f, 0.f, 0.f};

  float csum_local = 0.0f;
  const float scale = 2.0f / 255.0f;

  for (int kc = 0; kc < 4; ++kc) {
    __syncthreads();                           // staging of w (kc=0) / drain prev chunk
    // stage B chunk: Bt[o][klocal], klocal in [0,128). Coalesced W reads,
    // colsum accumulated on the fly (each thread has fixed o = t & 63).
    #pragma unroll
    for (int i = 0; i < 16; ++i) {
      int flat = t + 256 * i;                  // 0..4095
      int o = flat & 63;
      int kp = flat >> 6;                      // 0..63 -> klocal pair 2kp
      int c0 = kc * KCHUNK + 2 * kp;
      float v0 = (c0 < 496) ? Wm[c0 * 64 + o] : 0.0f;
      float v1 = (c0 + 1 < 496) ? Wm[(c0 + 1) * 64 + o] : 0.0f;
      csum_local += v0 + v1;
      unsigned packed = (unsigned)f2bf_rne(v0 * scale) |
                        ((unsigned)f2bf_rne(v1 * scale) << 16);
      *((unsigned*)&Bt[o * BST + 2 * kp]) = packed;
    }
    __syncthreads();

    #pragma unroll
    for (int ks = 0; ks < 4; ++ks) {
      const int k0 = kc * KCHUNK + ks * 32;
      // A fragments: A[m = l16][k = quad*8 + j] ; 8 consecutive fp32 -> bf16 (exact)
      short8 afrag[2];
      #pragma unroll
      for (int mt = 0; mt < 2; ++mt) {
        const float* src = &wlds[aBase + mt * 2 + k0];
        short8 f;
        #pragma unroll
        for (int j = 0; j < 8; ++j)
          f[j] = (short)(__float_as_uint(src[j]) >> 16);  // exact: ints <= 255
        afrag[mt] = f;
      }
      // B fragments: B[k = quad*8 + j][n = l16] ; aligned 16B LDS reads
      const int kloc = ks * 32 + 8 * quad;
      short8 bfrag[4];
      #pragma unroll
      for (int nt = 0; nt < 4; ++nt)
        bfrag[nt] = *((const short8*)&Bt[(nt * 16 + l16) * BST + kloc]);
      #pragma unroll
      for (int mt = 0; mt < 2; ++mt)
        #pragma unroll
        for (int nt = 0; nt < 4; ++nt)
          acc[mt][nt] = __builtin_amdgcn_mfma_f32_16x16x32_bf16(
              afrag[mt], bfrag[nt], acc[mt][nt], 0, 0, 0);
    }
  }

  // colsum reduction: part[t] covers o = t&63 over its c subset
  part[t] = csum_local;
  __syncthreads();
  if (t < 64)
    csum[t] = part[t] + part[t + 64] + part[t + 128] + part[t + 192];
  __syncthreads();

  // epilogue: C/D layout col = l16, row = quad*4 + reg
  float* outb = out + (long)bid * (128 * 64);
  #pragma unroll
  for (int mt = 0; mt < 2; ++mt) {
    int r0 = wave * 32 + mt * 16 + quad * 4;
    #pragma unroll
    for (int nt = 0; nt < 4; ++nt) {
      int o = nt * 16 + l16;
      float cs = csum[o];
      #pragma unroll
      for (int i = 0; i < 4; ++i)
        outb[(long)(r0 + i) * 64 + o] = acc[mt][nt][i] - cs;
    }
  }
}

extern "C" void kernel_launch(void* const* d_in, const int* in_sizes, int n_in,
                              void* d_out, int out_size, void* d_ws, size_t ws_size,
                              hipStream_t stream) {
  const int* x = (const int*)d_in[0];        // (256, 4096) bytes as int32
  const float* Wm = (const float*)d_in[1];   // (496, 64) fp32
  float* out = (float*)d_out;                // (256, 8, 128, 64) fp32
  byteformer_kernel<<<dim3(2048), dim3(256), 0, stream>>>(x, Wm, out);
}